// Round 4
// baseline (455.351 us; speedup 1.0000x reference)
//
#include <hip/hip_runtime.h>
#include <hip/hip_bf16.h>
#include <stdint.h>

#define PI_F 3.14159265358979f
#define EMBR 0.0275f
#define BATCH 1024
#define DIM 512
#define D2 1024
#define HID 2048
#define NB 30
#define K1 (NB * D2)          // 30720

using short8 = __attribute__((ext_vector_type(8))) short;
using f32x4  = __attribute__((ext_vector_type(4))) float;

// s_waitcnt: vmcnt lo [3:0], expcnt [6:4]=7 (ignore), lgkmcnt [11:8]=0xF (ignore), vmcnt hi [15:14]
#define WAITVM(N) __builtin_amdgcn_s_waitcnt(((N) & 0xF) | (((N) >> 4) << 14) | (0x7 << 4) | (0xF << 8))

__device__ __forceinline__ float bf2f(ushort u) {
  union { uint32_t i; float f; } v; v.i = ((uint32_t)u) << 16; return v.f;
}
__device__ __forceinline__ ushort f2bf(float f) {
  uint32_t u = __builtin_bit_cast(uint32_t, f);
  u += 0x7fffu + ((u >> 16) & 1u);   // RNE
  return (ushort)(u >> 16);
}

// async global->LDS, 16B per lane; LDS dest = wave-uniform base + lane*16
__device__ __forceinline__ void gld_lds16(const void* g, void* l) {
  __builtin_amdgcn_global_load_lds(
      (const __attribute__((address_space(1))) uint32_t*)(uintptr_t)g,
      (__attribute__((address_space(3))) uint32_t*)(uintptr_t)l, 16, 0, 0);
}

// ============ mega prep: rel_base transpose+cvt | prep | weight cvts ============
#define TR_BLKS 7680                    // (D2/64=16) x (K1/64=480)
#define PREP_BLKS 1024
#define W1F4 (HID * D2 / 4)
#define W2F4 (HID * HID / 4)
#define W0F4 (D2 * HID / 4)
#define WA1F4 (DIM * D2 / 4)
#define WA2F4 (D2 * DIM / 4)
#define CVT_BLKS ((W1F4 + W2F4 + W0F4 + WA1F4 + WA2F4) / 256)  // 9216

__global__ __launch_bounds__(256) void mega_prep(
    const float* __restrict__ rel_base, ushort* __restrict__ RBt,
    const float* __restrict__ axis, const float* __restrict__ argp,
    const int* __restrict__ rel, const float* __restrict__ rel_att,
    const float* __restrict__ rel_ax, const float* __restrict__ rel_ar,
    float* __restrict__ attb, ushort* __restrict__ Ebf, ushort* __restrict__ h0,
    const float* __restrict__ W1, const float* __restrict__ W2,
    const float* __restrict__ W0, const float* __restrict__ Wa1,
    const float* __restrict__ Wa2,
    ushort* __restrict__ W1b, ushort* __restrict__ W2b, ushort* __restrict__ W0b,
    ushort* __restrict__ Wa1b, ushort* __restrict__ Wa2b) {
  __shared__ ushort ts[64][68];
  const int bid = blockIdx.x, t = threadIdx.x;
  if (bid < TR_BLKS) {
    const int c0 = (bid & 15) * 64, r0 = (bid >> 4) * 64;
    const int tc = (t & 15) * 4;
    const int tr = t >> 4;
#pragma unroll
    for (int j = 0; j < 4; ++j) {
      const int r = tr + j * 16;
      float4 v = *(const float4*)&rel_base[(size_t)(r0 + r) * D2 + c0 + tc];
      ushort4 o;
      o.x = f2bf(v.x); o.y = f2bf(v.y); o.z = f2bf(v.z); o.w = f2bf(v.w);
      *(ushort4*)&ts[r][tc] = o;
    }
    __syncthreads();
#pragma unroll
    for (int j = 0; j < 4; ++j) {
      const int c = tr + j * 16;
      ushort4 v;
      v.x = ts[tc + 0][c]; v.y = ts[tc + 1][c];
      v.z = ts[tc + 2][c]; v.w = ts[tc + 3][c];
      *(ushort4*)&RBt[(size_t)(c0 + c) * K1 + r0 + tc] = v;
    }
  } else if (bid < TR_BLKS + PREP_BLKS) {
    const int b = bid - TR_BLKS;
    const int ri = rel[b];
    if (t < NB)
      attb[b * 32 + t] = tanhf(rel_att[ri * NB + t] * (1.f / EMBR)) * PI_F;
    for (int i = t; i < DIM; i += 256) {
      const float ax = axis[(size_t)b * DIM + i];
      const float ag = argp[(size_t)b * DIM + i];
      Ebf[(size_t)b * D2 + i]       = f2bf(ax);
      Ebf[(size_t)b * D2 + DIM + i] = f2bf(ag);
      const float ra = rel_ax[(size_t)ri * DIM + i];
      const float rg = rel_ar[(size_t)ri * DIM + i];
      h0[(size_t)b * D2 + i] = f2bf(ax + tanhf(ra * (1.f / EMBR)) * PI_F);
      h0[(size_t)b * D2 + DIM + i] =
          f2bf(ag + tanhf(2.f * rg * (1.f / EMBR)) * (PI_F * 0.5f) + PI_F * 0.5f);
    }
  } else {
    int i = (bid - TR_BLKS - PREP_BLKS) * 256 + t;
    const float* s; ushort* d;
    if (i < W1F4) { s = W1; d = W1b; }
    else if ((i -= W1F4) < W2F4) { s = W2; d = W2b; }
    else if ((i -= W2F4) < W0F4) { s = W0; d = W0b; }
    else if ((i -= W0F4) < WA1F4) { s = Wa1; d = Wa1b; }
    else { i -= WA1F4; s = Wa2; d = Wa2b; }
    float4 v = ((const float4*)s)[i];
    ushort4 o;
    o.x = f2bf(v.x); o.y = f2bf(v.y); o.z = f2bf(v.z); o.w = f2bf(v.w);
    ((ushort4*)d)[i] = o;
  }
}

// ======= split-K NT GEMM, 3-buffer pipeline: Cf[z] = A[:,zslice] @ Bt[:,zslice]^T =======
__global__ __launch_bounds__(256, 3) void gemm_nt(
    const ushort* __restrict__ A, const ushort* __restrict__ Bt,
    float* __restrict__ Cf, int M, int N, int K, int kLen) {
  __shared__ ushort As[3][128 * 32];
  __shared__ ushort Bs[3][128 * 32];
  const int tid  = threadIdx.x;
  const int lane = tid & 63, wave = tid >> 6;
  const int wm = wave >> 1, wn = wave & 1;
  const int lrow = lane & 15, quad = lane >> 4;
  const int m0 = blockIdx.y * 128, n0 = blockIdx.x * 128;
  const int kStart = blockIdx.z * kLen;
  const int T = kLen >> 5;

  const int rr = lane >> 2;
  const int eo = (lane & 3) * 8;
  const int c1 = wave, c2 = wave + 4;
  const ushort* Ag1 = A  + (size_t)(m0 + c1 * 16 + rr) * K + kStart + eo;
  const ushort* Ag2 = A  + (size_t)(m0 + c2 * 16 + rr) * K + kStart + eo;
  const ushort* Bg1 = Bt + (size_t)(n0 + c1 * 16 + rr) * K + kStart + eo;
  const ushort* Bg2 = Bt + (size_t)(n0 + c2 * 16 + rr) * K + kStart + eo;

  auto issue = [&](int slot) {
    const int tt = (slot < T - 1) ? slot : T - 1;
    const int bf = slot % 3;
    const int kk = tt << 5;
    gld_lds16(Ag1 + kk, &As[bf][c1 * 512]);
    gld_lds16(Ag2 + kk, &As[bf][c2 * 512]);
    gld_lds16(Bg1 + kk, &Bs[bf][c1 * 512]);
    gld_lds16(Bg2 + kk, &Bs[bf][c2 * 512]);
  };

  f32x4 acc[4][4] = {};
  issue(0); issue(1);

  for (int t = 0; t < T; ++t) {
    WAITVM(4);
    __builtin_amdgcn_s_barrier();
    issue(t + 2);
    const ushort* as = As[t % 3];
    const ushort* bs = Bs[t % 3];
    short8 af[4], bq[4];
#pragma unroll
    for (int i = 0; i < 4; ++i) {
      af[i] = *(const short8*)&as[(wm * 64 + i * 16 + lrow) * 32 + quad * 8];
      bq[i] = *(const short8*)&bs[(wn * 64 + i * 16 + lrow) * 32 + quad * 8];
    }
#pragma unroll
    for (int mi = 0; mi < 4; ++mi)
#pragma unroll
      for (int ni = 0; ni < 4; ++ni)
        acc[mi][ni] = __builtin_amdgcn_mfma_f32_16x16x32_bf16(
            af[mi], bq[ni], acc[mi][ni], 0, 0, 0);
  }
  WAITVM(0);

  float* dst = Cf + (size_t)blockIdx.z * M * N;
  const int colBase = n0 + wn * 64;
  const int rowBase = m0 + wm * 64;
#pragma unroll
  for (int mi = 0; mi < 4; ++mi)
#pragma unroll
    for (int ni = 0; ni < 4; ++ni) {
      const int col  = colBase + ni * 16 + lrow;
      const int row0 = rowBase + mi * 16 + quad * 4;
#pragma unroll
      for (int g = 0; g < 4; ++g)
        dst[(size_t)(row0 + g) * N + col] = acc[mi][ni][g];
    }
}

// ==== rtrans GEMM: one r per z; Pb[z] = bf16( att[:,z] * (e @ RB_z) ) ====
__global__ __launch_bounds__(256, 3) void gemm_rtrans(
    const ushort* __restrict__ E, const ushort* __restrict__ RBt,
    const float* __restrict__ attb, ushort* __restrict__ Pb) {
  __shared__ ushort As[3][128 * 32];
  __shared__ ushort Bs[3][128 * 32];
  __shared__ float attS[128];
  const int tid  = threadIdx.x;
  const int lane = tid & 63, wave = tid >> 6;
  const int wm = wave >> 1, wn = wave & 1;
  const int lrow = lane & 15, quad = lane >> 4;
  const int m0 = blockIdx.y * 128, n0 = blockIdx.x * 128;
  const int z = blockIdx.z;                     // base index r
  const int T = 32;                             // 1024 / 32

  if (tid < 128) attS[tid] = attb[(size_t)(m0 + tid) * 32 + z];
  __syncthreads();

  const int rr = lane >> 2;
  const int eo = (lane & 3) * 8;
  const int c1 = wave, c2 = wave + 4;
  const ushort* Ag1 = E + (size_t)(m0 + c1 * 16 + rr) * D2 + eo;
  const ushort* Ag2 = E + (size_t)(m0 + c2 * 16 + rr) * D2 + eo;
  const ushort* Bg1 = RBt + (size_t)(n0 + c1 * 16 + rr) * K1 + ((size_t)z << 10) + eo;
  const ushort* Bg2 = RBt + (size_t)(n0 + c2 * 16 + rr) * K1 + ((size_t)z << 10) + eo;

  auto issue = [&](int slot) {
    const int tt = (slot < T - 1) ? slot : T - 1;
    const int bf = slot % 3;
    const int kk = tt << 5;
    gld_lds16(Ag1 + kk, &As[bf][c1 * 512]);
    gld_lds16(Ag2 + kk, &As[bf][c2 * 512]);
    gld_lds16(Bg1 + kk, &Bs[bf][c1 * 512]);
    gld_lds16(Bg2 + kk, &Bs[bf][c2 * 512]);
  };

  f32x4 acc[4][4] = {};
  issue(0); issue(1);

  for (int t = 0; t < T; ++t) {
    WAITVM(4);
    __builtin_amdgcn_s_barrier();
    issue(t + 2);
    const ushort* as = As[t % 3];
    const ushort* bs = Bs[t % 3];
    short8 af[4], bq[4];
#pragma unroll
    for (int i = 0; i < 4; ++i) {
      af[i] = *(const short8*)&as[(wm * 64 + i * 16 + lrow) * 32 + quad * 8];
      bq[i] = *(const short8*)&bs[(wn * 64 + i * 16 + lrow) * 32 + quad * 8];
    }
#pragma unroll
    for (int mi = 0; mi < 4; ++mi)
#pragma unroll
      for (int ni = 0; ni < 4; ++ni)
        acc[mi][ni] = __builtin_amdgcn_mfma_f32_16x16x32_bf16(
            af[mi], bq[ni], acc[mi][ni], 0, 0, 0);
  }
  WAITVM(0);

  ushort* dst = Pb + (size_t)z * BATCH * D2;
  const int colBase = n0 + wn * 64;
  const int rowBase = m0 + wm * 64;
#pragma unroll
  for (int mi = 0; mi < 4; ++mi)
#pragma unroll
    for (int ni = 0; ni < 4; ++ni) {
      const int col  = colBase + ni * 16 + lrow;
      const int row0 = rowBase + mi * 16 + quad * 4;
#pragma unroll
      for (int g = 0; g < 4; ++g) {
        const float s = attS[wm * 64 + mi * 16 + quad * 4 + g];
        dst[(size_t)(row0 + g) * D2 + col] = f2bf(s * acc[mi][ni][g]);
      }
    }
}

// ------- reduce 30 bf16 partials + att@rel_bias + LayerNorm -> xrt, Xb row -------
__global__ __launch_bounds__(256) void reduce_ln_rt(
    const ushort* __restrict__ Pb, const float* __restrict__ att,
    const float* __restrict__ rel_bias, float* __restrict__ xf,
    ushort* __restrict__ Xb) {
  const int b = blockIdx.x, t = threadIdx.x;
  __shared__ float attS[NB];
  __shared__ float sa[4], sb[4];
  if (t < NB) attS[t] = att[b * 32 + t];
  __syncthreads();
  const int o0 = t * 4;
  float v[4] = {};
#pragma unroll
  for (int r = 0; r < NB; ++r) {
    ushort4 p = *(const ushort4*)&Pb[((size_t)r * BATCH + b) * D2 + o0];
    v[0] += bf2f(p.x); v[1] += bf2f(p.y); v[2] += bf2f(p.z); v[3] += bf2f(p.w);
  }
#pragma unroll
  for (int r = 0; r < NB; ++r) {
    const float a = attS[r];
    float4 rb = *(const float4*)&rel_bias[(size_t)r * D2 + o0];
    v[0] += a * rb.x; v[1] += a * rb.y; v[2] += a * rb.z; v[3] += a * rb.w;
  }
  float sum = v[0] + v[1] + v[2] + v[3];
  float sq  = v[0]*v[0] + v[1]*v[1] + v[2]*v[2] + v[3]*v[3];
  const int lane = t & 63, wv = t >> 6;
  for (int off = 32; off > 0; off >>= 1) {
    sum += __shfl_down(sum, off, 64);
    sq  += __shfl_down(sq, off, 64);
  }
  if (lane == 0) { sa[wv] = sum; sb[wv] = sq; }
  __syncthreads();
  const float S = sa[0] + sa[1] + sa[2] + sa[3];
  const float Q = sb[0] + sb[1] + sb[2] + sb[3];
  const float mean = S / D2;
  const float inv = rsqrtf(fmaxf(Q / D2 - mean * mean, 0.f) + 1e-5f);
  float4 yo; ushort4 yb;
  yo.x = (v[0] - mean) * inv; yb.x = f2bf(yo.x);
  yo.y = (v[1] - mean) * inv; yb.y = f2bf(yo.y);
  yo.z = (v[2] - mean) * inv; yb.z = f2bf(yo.z);
  yo.w = (v[3] - mean) * inv; yb.w = f2bf(yo.w);
  *(float4*)&xf[(size_t)b * D2 + o0] = yo;
  *(ushort4*)&Xb[(size_t)b * D2 + o0] = yb;
}

// ---- reduce S fp32 partials + bias + relu -> bf16 (H1 / H2 / Aat) ----
__global__ __launch_bounds__(256) void reduce_relu_bf16(
    const float* __restrict__ P, const float* __restrict__ bias,
    ushort* __restrict__ out, int S, int MN, int N) {
  const int i = blockIdx.x * 256 + threadIdx.x;
  const int e0 = i * 4;
  if (e0 >= MN) return;
  float4 a = ((const float4*)P)[i];
  for (int s = 1; s < S; ++s) {
    float4 p = *(const float4*)&P[(size_t)s * MN + e0];
    a.x += p.x; a.y += p.y; a.z += p.z; a.w += p.w;
  }
  float4 bv = *(const float4*)&bias[e0 & (N - 1)];
  ushort4 o;
  o.x = f2bf(fmaxf(a.x + bv.x, 0.f));
  o.y = f2bf(fmaxf(a.y + bv.y, 0.f));
  o.z = f2bf(fmaxf(a.z + bv.z, 0.f));
  o.w = f2bf(fmaxf(a.w + bv.w, 0.f));
  ((ushort4*)out)[i] = o;
}

// ---- reduce S partials + b0 + LayerNorm (mlp branch) -> xml, Xb row ----
__global__ __launch_bounds__(256) void ln_rows(
    const float* __restrict__ P, const float* __restrict__ b0, int S,
    float* __restrict__ xf, ushort* __restrict__ Xb) {
  const int b = blockIdx.x, t = threadIdx.x;
  __shared__ float sa[4], sb[4];
  const int o0 = t * 4;
  float4 a = *(const float4*)&P[(size_t)b * D2 + o0];
  for (int s = 1; s < S; ++s) {
    float4 p = *(const float4*)&P[(size_t)s * BATCH * D2 + (size_t)b * D2 + o0];
    a.x += p.x; a.y += p.y; a.z += p.z; a.w += p.w;
  }
  float4 bv = *(const float4*)&b0[o0];
  float v[4] = {a.x + bv.x, a.y + bv.y, a.z + bv.z, a.w + bv.w};
  float sum = v[0] + v[1] + v[2] + v[3];
  float sq  = v[0]*v[0] + v[1]*v[1] + v[2]*v[2] + v[3]*v[3];
  const int lane = t & 63, wv = t >> 6;
  for (int off = 32; off > 0; off >>= 1) {
    sum += __shfl_down(sum, off, 64);
    sq  += __shfl_down(sq, off, 64);
  }
  if (lane == 0) { sa[wv] = sum; sb[wv] = sq; }
  __syncthreads();
  const float S_ = sa[0] + sa[1] + sa[2] + sa[3];
  const float Q  = sb[0] + sb[1] + sb[2] + sb[3];
  const float mean = S_ / D2;
  const float inv = rsqrtf(fmaxf(Q / D2 - mean * mean, 0.f) + 1e-5f);
  float4 yo; ushort4 yb;
  yo.x = (v[0] - mean) * inv; yb.x = f2bf(yo.x);
  yo.y = (v[1] - mean) * inv; yb.y = f2bf(yo.y);
  yo.z = (v[2] - mean) * inv; yb.z = f2bf(yo.z);
  yo.w = (v[3] - mean) * inv; yb.w = f2bf(yo.w);
  *(float4*)&xf[(size_t)b * D2 + o0] = yo;
  *(ushort4*)&Xb[(size_t)b * D2 + o0] = yb;
}

// ---- reduce S partials of Lg + ba2, softmax over 2 branches, merge, activations ----
__global__ __launch_bounds__(256) void fuse_out(
    const float* __restrict__ P, const float* __restrict__ ba2, int S,
    const float* __restrict__ xrt, const float* __restrict__ xml,
    float* __restrict__ out) {
  const int b = blockIdx.x, t = threadIdx.x;
  const int o0 = t * 4;
  float4 l0 = *(const float4*)&P[(size_t)b * D2 + o0];
  float4 l1 = *(const float4*)&P[(size_t)(BATCH + b) * D2 + o0];
  for (int s = 1; s < S; ++s) {
    const float* Ps = P + (size_t)s * 2 * BATCH * D2;
    float4 p0 = *(const float4*)&Ps[(size_t)b * D2 + o0];
    float4 p1 = *(const float4*)&Ps[(size_t)(BATCH + b) * D2 + o0];
    l0.x += p0.x; l0.y += p0.y; l0.z += p0.z; l0.w += p0.w;
    l1.x += p1.x; l1.y += p1.y; l1.z += p1.z; l1.w += p1.w;
  }
  float4 xr = *(const float4*)&xrt[(size_t)b * D2 + o0];
  float4 xm = *(const float4*)&xml[(size_t)b * D2 + o0];
  float r[4];
#pragma unroll
  for (int j = 0; j < 4; ++j) {
    const float a0 = ((const float*)&l0)[j];
    const float a1 = ((const float*)&l1)[j];
    const float w0 = 1.f / (1.f + expf(a1 - a0));
    const float m = w0 * ((const float*)&xr)[j] + (1.f - w0) * ((const float*)&xm)[j];
    r[j] = (o0 < DIM) ? tanhf(m) * PI_F
                      : tanhf(2.f * m) * (PI_F * 0.5f) + PI_F * 0.5f;
  }
  float* dst = (o0 < DIM)
      ? &out[(size_t)b * DIM + o0]
      : &out[(size_t)BATCH * DIM + (size_t)b * DIM + (o0 - DIM)];
  *(float4*)dst = {r[0], r[1], r[2], r[3]};
}

extern "C" void kernel_launch(void* const* d_in, const int* in_sizes, int n_in,
                              void* d_out, int out_size, void* d_ws, size_t ws_size,
                              hipStream_t stream) {
  (void)in_sizes; (void)n_in; (void)out_size; (void)ws_size;
  const float* s_axis   = (const float*)d_in[0];
  const float* s_arg    = (const float*)d_in[1];
  const int*   rel      = (const int*)d_in[2];
  const float* rel_base = (const float*)d_in[3];
  const float* rel_att  = (const float*)d_in[4];
  const float* rel_bias = (const float*)d_in[5];
  const float* rel_ax_e = (const float*)d_in[6];
  const float* rel_ar_e = (const float*)d_in[7];
  const float* W1 = (const float*)d_in[8];
  const float* b1 = (const float*)d_in[9];
  const float* W2 = (const float*)d_in[10];
  const float* b2 = (const float*)d_in[11];
  const float* W0 = (const float*)d_in[12];
  const float* b0 = (const float*)d_in[13];
  const float* Wa1 = (const float*)d_in[14];
  const float* ba1 = (const float*)d_in[15];
  const float* Wa2 = (const float*)d_in[16];
  const float* ba2 = (const float*)d_in[17];

  char* ws = (char*)d_ws;
  size_t off = 0;
  ushort* RBt  = (ushort*)(ws + off); off += (size_t)K1 * D2 * 2;            // 63 MB
  char*   Pzone= ws + off;            off += (size_t)NB * BATCH * D2 * 2;    // 61.4 MB
  ushort* Pb   = (ushort*)Pzone;       // rtrans bf16 partials (30 slices)
  float*  P    = (float*)Pzone;        // later: fp32 split-K partials (<=32 MB)
  ushort* Ebf  = (ushort*)(ws + off); off += (size_t)BATCH * D2 * 2;
  ushort* W1b  = (ushort*)(ws + off); off += (size_t)HID * D2 * 2;
  ushort* W2b  = (ushort*)(ws + off); off += (size_t)HID * HID * 2;
  ushort* W0b  = (ushort*)(ws + off); off += (size_t)D2 * HID * 2;
  ushort* Wa1b = (ushort*)(ws + off); off += (size_t)DIM * D2 * 2;
  ushort* Wa2b = (ushort*)(ws + off); off += (size_t)D2 * DIM * 2;
  ushort* h0   = (ushort*)(ws + off); off += (size_t)BATCH * D2 * 2;
  ushort* Xb   = (ushort*)(ws + off); off += (size_t)2 * BATCH * D2 * 2;
  ushort* H1   = (ushort*)(ws + off); off += (size_t)BATCH * HID * 2;
  ushort* H2   = (ushort*)(ws + off); off += (size_t)BATCH * HID * 2;
  ushort* Aat  = (ushort*)(ws + off); off += (size_t)2 * BATCH * DIM * 2;
  float*  xrt  = (float*)(ws + off);  off += (size_t)BATCH * D2 * 4;
  float*  xml  = (float*)(ws + off);  off += (size_t)BATCH * D2 * 4;
  float*  attb = (float*)(ws + off);  off += (size_t)BATCH * 32 * 4;

  mega_prep<<<TR_BLKS + PREP_BLKS + CVT_BLKS, 256, 0, stream>>>(
      rel_base, RBt, s_axis, s_arg, rel, rel_att, rel_ax_e, rel_ar_e,
      attb, Ebf, h0, W1, W2, W0, Wa1, Wa2, W1b, W2b, W0b, Wa1b, Wa2b);

  // rtrans branch
  gemm_rtrans<<<dim3(D2 / 128, BATCH / 128, NB), 256, 0, stream>>>(
      Ebf, RBt, attb, Pb);
  reduce_ln_rt<<<BATCH, 256, 0, stream>>>(Pb, attb, rel_bias, xrt, Xb);

  // mlp branch (split-K GEMMs -> fp32 partials in P -> fused reduce epilogues)
  gemm_nt<<<dim3(HID / 128, BATCH / 128, 4), 256, 0, stream>>>(
      h0, W1b, P, BATCH, HID, D2, D2 / 4);
  reduce_relu_bf16<<<BATCH * HID / 1024, 256, 0, stream>>>(
      P, b1, H1, 4, BATCH * HID, HID);
  gemm_nt<<<dim3(HID / 128, BATCH / 128, 4), 256, 0, stream>>>(
      H1, W2b, P, BATCH, HID, HID, HID / 4);
  reduce_relu_bf16<<<BATCH * HID / 1024, 256, 0, stream>>>(
      P, b2, H2, 4, BATCH * HID, HID);
  gemm_nt<<<dim3(D2 / 128, BATCH / 128, 8), 256, 0, stream>>>(
      H2, W0b, P, BATCH, D2, HID, HID / 8);
  ln_rows<<<BATCH, 256, 0, stream>>>(P, b0, 8, xml, Xb + (size_t)BATCH * D2);

  // attention fusion (both branches stacked: M = 2*BATCH)
  gemm_nt<<<dim3(DIM / 128, 2 * BATCH / 128, 8), 256, 0, stream>>>(
      Xb, Wa1b, P, 2 * BATCH, DIM, D2, D2 / 8);
  reduce_relu_bf16<<<2 * BATCH * DIM / 1024, 256, 0, stream>>>(
      P, ba1, Aat, 8, 2 * BATCH * DIM, DIM);
  gemm_nt<<<dim3(D2 / 128, 2 * BATCH / 128, 4), 256, 0, stream>>>(
      Aat, Wa2b, P, 2 * BATCH, D2, DIM, DIM / 4);
  fuse_out<<<BATCH, 256, 0, stream>>>(P, ba2, 4, xrt, xml, (float*)d_out);
}